// Round 4
// baseline (57050.195 us; speedup 1.0000x reference)
//
#include <hip/hip_runtime.h>
#include <math.h>

#define NN 4096
#define TT 365
#define FF 16
#define HH 32
#define NB 256

typedef _Float16 f16;
typedef __attribute__((ext_vector_type(8))) _Float16 f16x8;
typedef __attribute__((ext_vector_type(4))) float f32x4;

__device__ __forceinline__ float sigf(float x){ return 1.0f/(1.0f+__expf(-x)); }
__device__ __forceinline__ float thf(float x){
    x = fminf(fmaxf(x,-15.0f),15.0f);
    float e = __expf(2.0f*x);
    return (e-1.0f)/(e+1.0f);
}

// Pre-pack A (fp32 [4096][4096]) into MFMA A-fragment order, single fp16.
// Fragment addr (f16x8 units): (rb*128 + kt)*64 + lane
__global__ __launch_bounds__(256)
void prep_A(const float* __restrict__ A, f16* __restrict__ Af){
    size_t i = (size_t)blockIdx.x*256 + threadIdx.x;   // 2,097,152 f16x8 frags
    int lane = (int)(i & 63);
    int kt   = (int)((i>>6) & 127);
    int rb   = (int)(i>>13);
    int m  = rb*16 + (lane&15);
    int k0 = kt*32 + ((lane>>4)<<3);
    const float* src = A + (size_t)m*NN + k0;
    float4 a = *(const float4*)src;
    float4 b = *(const float4*)(src+4);
    float v[8] = {a.x,a.y,a.z,a.w,b.x,b.y,b.z,b.w};
    f16x8 vh;
    #pragma unroll
    for (int j=0;j<8;++j) vh[j] = (f16)v[j];
    ((f16x8*)Af)[i] = vh;
}

// Initial G (h=c=0 -> cols = biases), fragment-ordered fp16; zero barrier counter.
__global__ __launch_bounds__(256)
void init_G(f16* __restrict__ G, const float* __restrict__ bgh,
            const float* __restrict__ bgc, int* __restrict__ cnt){
    int i = blockIdx.x*256 + threadIdx.x;   // k*64+n
    int k = i>>6, n = i&63;
    float v = (n<HH) ? bgh[n] : bgc[n-HH];
    int kt = k>>5, kr = k&31;
    size_t idx = (((size_t)kt*4 + (n>>4))*64 + ((n&15) + ((kr>>3)<<4)))*8 + (kr&7);
    G[idx] = (f16)v;
    if (i == 0) *cnt = 0;
}

// Persistent kernel: whole T-loop inside, manual grid barrier between steps.
// 256 blocks x 512 threads, 1 block/CU. Block owns 16 node-rows.
__global__ __launch_bounds__(512)
void fused_kernel(const f16* __restrict__ Af, f16* __restrict__ G0, f16* __restrict__ G1,
                  const float* __restrict__ x, const float* __restrict__ W_out,
                  const float* __restrict__ b_out,
                  const float* __restrict__ Wgh, const float* __restrict__ bgh,
                  const float* __restrict__ Wgc, const float* __restrict__ bgc,
                  const float* __restrict__ Whc, const float* __restrict__ Whp,
                  const float* __restrict__ bh,
                  const float* __restrict__ Wcc, const float* __restrict__ Wcp,
                  const float* __restrict__ bc,
                  const float* __restrict__ K, const float* __restrict__ R,
                  const float* __restrict__ bias,
                  float* __restrict__ out, int* cnt)
{
    __shared__ float smem[12656];            // 50.6 KB
    float* ldsRed = smem;                    // [8][16][64] phase-1 partials
    float* gts    = smem;                    // alias: [16][129] gates
    float* hgcg   = smem + 8192;             // [16][65]
    float* hst    = smem + 9232;             // [2][16*33] persistent h state
    float* cst    = smem + 10288;            // [2][16*33] persistent c state
    float* hcur   = smem + 11344;            // [16*33]
    float* ccur   = smem + 11872;
    float* xs     = smem + 12400;            // [16][16]

    const int tid  = threadIdx.x;
    const int w    = tid >> 6;               // wave = k-eighth
    const int lane = tid & 63;
    const int rb   = blockIdx.x;

    // zero persistent state (both parities)
    for (int i = tid; i < 2112; i += 512) smem[9232 + i] = 0.f;

    const f16x8* Ahp = (const f16x8*)Af;
    const size_t aBase = ((size_t)rb*128 + w*16)*64 + lane;
    f16x8 aPre[8];
    #pragma unroll
    for (int i = 0; i < 8; ++i) aPre[i] = Ahp[aBase + (size_t)i*64];

    // phase-2 thread mapping: 1 h-dim per thread, row = 32-lane group
    const int r2 = tid >> 5;                 // local row 0..15
    const int j  = tid & 31;                 // h-dim 0..31
    const int row = rb*16 + r2;

    for (int t = 0; t < TT; ++t){
        const f16x8* Gf = (const f16x8*)((t&1) ? G1 : G0);
        f16* Gout = (t&1) ? G0 : G1;

        // ---------------- phase 1: fp16 MFMA, wave w = k-slice ----------------
        f32x4 acc[4] = {};
        const size_t gBase = ((size_t)w*64)*64 + lane;
        #pragma unroll
        for (int kt = 0; kt < 16; ++kt){
            f16x8 ah = (kt < 8) ? aPre[kt] : Ahp[aBase + (size_t)kt*64];
            size_t gI = gBase + (size_t)kt*256;
            f16x8 g0 = Gf[gI], g1 = Gf[gI+64], g2 = Gf[gI+128], g3 = Gf[gI+192];
            acc[0] = __builtin_amdgcn_mfma_f32_16x16x32_f16(ah,g0,acc[0],0,0,0);
            acc[1] = __builtin_amdgcn_mfma_f32_16x16x32_f16(ah,g1,acc[1],0,0,0);
            acc[2] = __builtin_amdgcn_mfma_f32_16x16x32_f16(ah,g2,acc[2],0,0,0);
            acc[3] = __builtin_amdgcn_mfma_f32_16x16x32_f16(ah,g3,acc[3],0,0,0);
        }
        #pragma unroll
        for (int ct = 0; ct < 4; ++ct)
            #pragma unroll
            for (int r = 0; r < 4; ++r){
                int mrow = ((lane>>4)<<2) + r;
                int mcol = ct*16 + (lane&15);
                ldsRed[(w<<10) + mrow*64 + mcol] = acc[ct][r];
            }
        __syncthreads();
        {   // reduce 8 wave-partials + tanh
            int o = tid*2;
            #pragma unroll
            for (int q = 0; q < 2; ++q){
                int oo = o + q;
                float s = 0.f;
                #pragma unroll
                for (int ww = 0; ww < 8; ++ww) s += ldsRed[(ww<<10) + oo];
                hgcg[(oo>>6)*65 + (oo&63)] = thf(s);
            }
        }
        __syncthreads();

        // prefetch A fragments for next step (independent of G)
        if (t+1 < TT){
            #pragma unroll
            for (int i = 0; i < 8; ++i) aPre[i] = Ahp[aBase + (size_t)i*64];
        }

        // ---------------- phase 2: all 512 threads, 1 dim each ----------------
        // All cross-thread LDS reads below stay within one 32-lane row group
        // (in-order within a wave) -> no __syncthreads needed.
        float* hPrv = hst + (t&1)*528;
        float* cPrv = cst + (t&1)*528;
        float* hNxt = hst + ((t+1)&1)*528;
        float* cNxt = cst + ((t+1)&1)*528;

        if (j < 16) xs[r2*16 + j] = x[((size_t)row*TT + t)*FF + j];

        // gates: thread computes gate cols [j*4, j*4+4)
        float g4[4];
        #pragma unroll
        for (int q = 0; q < 4; ++q) g4[q] = bias[j*4 + q];
        #pragma unroll
        for (int f = 0; f < FF; ++f){
            float xv = xs[r2*16 + f];
            float4 k4 = *(const float4*)(K + f*128 + j*4);
            g4[0] += xv*k4.x; g4[1] += xv*k4.y; g4[2] += xv*k4.z; g4[3] += xv*k4.w;
        }
        #pragma unroll
        for (int i = 0; i < HH; ++i){
            float hv = hPrv[r2*33 + i];
            float4 r4 = *(const float4*)(R + i*128 + j*4);
            g4[0] += hv*r4.x; g4[1] += hv*r4.y; g4[2] += hv*r4.z; g4[3] += hv*r4.w;
        }
        #pragma unroll
        for (int q = 0; q < 4; ++q) gts[r2*129 + j*4 + q] = g4[q];

        // LSTM cell, dim j (gate order i,f,g,o)
        float gi = gts[r2*129 + j],      gf = gts[r2*129 + 32 + j];
        float gg = gts[r2*129 + 64 + j], go = gts[r2*129 + 96 + j];
        float cc = sigf(gf)*cPrv[r2*33 + j] + sigf(gi)*thf(gg);
        float hc = sigf(go)*thf(cc);
        hcur[r2*33 + j] = hc;
        ccur[r2*33 + j] = cc;

        // fusion
        float s = bh[j], u = bc[j];
        #pragma unroll
        for (int i = 0; i < HH; ++i){
            float hcv = hcur[r2*33 + i], hgv = hgcg[r2*65 + i];
            float ccv = ccur[r2*33 + i], cgv = hgcg[r2*65 + 32 + i];
            s += hcv*Whc[i*32 + j] + hgv*Whp[i*32 + j];
            u += ccv*Wcc[i*32 + j] + cgv*Wcp[i*32 + j];
        }
        float hu = sigf(s), cu = sigf(u);
        hNxt[r2*33 + j] = hu;
        cNxt[r2*33 + j] = cu;

        // G(t+1), written straight into B-fragment order
        float gh = bgh[j], gc = bgc[j];
        #pragma unroll
        for (int i = 0; i < HH; ++i){
            float hv = hNxt[r2*33 + i], cv = cNxt[r2*33 + i];
            gh += hv*Wgh[i*32 + j];
            gc += cv*Wgc[i*32 + j];
        }
        {
            const int kt = row>>5, kr = row&31;
            const size_t tb = ((size_t)kt*4)*64;
            size_t i0 = (tb + (size_t)(j>>4)*64 + ((j&15) + ((kr>>3)<<4)))*8 + (kr&7);
            size_t i1 = (tb + (size_t)((HH+j)>>4)*64 + ((j&15) + ((kr>>3)<<4)))*8 + (kr&7);
            Gout[i0] = (f16)gh;
            Gout[i1] = (f16)gc;
        }

        // fused output head
        float p = hu * W_out[j];
        #pragma unroll
        for (int off = 16; off; off >>= 1) p += __shfl_down(p, off, 32);
        if (j == 0) out[(size_t)t*NN + row] = p + b_out[0];

        // ---------------- grid barrier ----------------
        __threadfence();
        __syncthreads();
        if (tid == 0){
            __hip_atomic_fetch_add(cnt, 1, __ATOMIC_ACQ_REL, __HIP_MEMORY_SCOPE_AGENT);
            int target = (t+1)*NB;
            while (__hip_atomic_load(cnt, __ATOMIC_ACQUIRE, __HIP_MEMORY_SCOPE_AGENT) < target)
                __builtin_amdgcn_s_sleep(2);
        }
        __syncthreads();
        __threadfence();
    }
}

extern "C" void kernel_launch(void* const* d_in, const int* in_sizes, int n_in,
                              void* d_out, int out_size, void* d_ws, size_t ws_size,
                              hipStream_t stream)
{
    const float* x     = (const float*)d_in[0];
    const float* A     = (const float*)d_in[1];
    const float* W_out = (const float*)d_in[2];
    const float* b_out = (const float*)d_in[3];
    const float* Wgh   = (const float*)d_in[4];
    const float* bgh   = (const float*)d_in[5];
    const float* Wgc   = (const float*)d_in[6];
    const float* bgc   = (const float*)d_in[7];
    const float* Whc   = (const float*)d_in[8];
    const float* Whp   = (const float*)d_in[9];
    const float* bh    = (const float*)d_in[10];
    const float* Wcc   = (const float*)d_in[11];
    const float* Wcp   = (const float*)d_in[12];
    const float* bc    = (const float*)d_in[13];
    const float* K     = (const float*)d_in[14];
    const float* R     = (const float*)d_in[15];
    const float* bias  = (const float*)d_in[16];
    float* out = (float*)d_out;

    // ws: Af 32MB | G double-buffer 2x512KB | barrier counter
    f16* Af = (f16*)d_ws;
    f16* G0 = Af + (size_t)NN*NN;
    f16* G1 = G0 + (size_t)NN*64;
    int* cnt = (int*)(G1 + (size_t)NN*64);

    prep_A<<<dim3(8192), dim3(256), 0, stream>>>(A, Af);
    init_G<<<dim3(1024), dim3(256), 0, stream>>>(G0, bgh, bgc, cnt);

    void* args[] = {
        (void*)&Af, (void*)&G0, (void*)&G1, (void*)&x, (void*)&W_out, (void*)&b_out,
        (void*)&Wgh, (void*)&bgh, (void*)&Wgc, (void*)&bgc,
        (void*)&Whc, (void*)&Whp, (void*)&bh,
        (void*)&Wcc, (void*)&Wcp, (void*)&bc,
        (void*)&K, (void*)&R, (void*)&bias, (void*)&out, (void*)&cnt
    };
    hipLaunchCooperativeKernel((const void*)fused_kernel, dim3(NB), dim3(512),
                               args, 0, stream);
}

// Round 5
// 6363.773 us; speedup vs baseline: 8.9648x; 8.9648x over previous
//
#include <hip/hip_runtime.h>
#include <math.h>

#define NN 4096
#define TT 365
#define FF 16
#define HH 32

typedef _Float16 f16;
typedef __attribute__((ext_vector_type(8))) _Float16 f16x8;
typedef __attribute__((ext_vector_type(4))) float f32x4;

__device__ __forceinline__ float sigf(float x){ return 1.0f/(1.0f+__expf(-x)); }
__device__ __forceinline__ float thf(float x){
    x = fminf(fmaxf(x,-15.0f),15.0f);
    float e = __expf(2.0f*x);
    return (e-1.0f)/(e+1.0f);
}

// Pre-pack A (fp32 [4096][4096]) into MFMA A-fragment order, single fp16.
// Fragment addr (f16x8 units): (rb*128 + kt)*64 + lane
//   lane&15 = local row m, lane>>4 = k-subgroup (8 consecutive k each).
__global__ __launch_bounds__(256)
void prep_A(const float* __restrict__ A, f16* __restrict__ Af){
    size_t i = (size_t)blockIdx.x*256 + threadIdx.x;   // 2,097,152 f16x8 frags
    int lane = (int)(i & 63);
    int kt   = (int)((i>>6) & 127);
    int rb   = (int)(i>>13);
    int m  = rb*16 + (lane&15);
    int k0 = kt*32 + ((lane>>4)<<3);
    const float* src = A + (size_t)m*NN + k0;
    float4 a = *(const float4*)src;
    float4 b = *(const float4*)(src+4);
    float v[8] = {a.x,a.y,a.z,a.w,b.x,b.y,b.z,b.w};
    f16x8 vh;
    #pragma unroll
    for (int j=0;j<8;++j) vh[j] = (f16)v[j];
    ((f16x8*)Af)[i] = vh;
}

// Initial G (h=c=0 -> cols = biases), fragment-ordered fp16; zero h/c state.
// B-fragment addr (f16 units): ((kt*4 + ct)*64 + (n&15) + ((kr>>3)<<4))*8 + (kr&7)
__global__ __launch_bounds__(256)
void init_G(f16* __restrict__ G, float* __restrict__ hs, float* __restrict__ cs,
            const float* __restrict__ bgh, const float* __restrict__ bgc){
    int i = blockIdx.x*256 + threadIdx.x;   // k*64+n
    int k = i>>6, n = i&63;
    float v = (n<HH) ? bgh[n] : bgc[n-HH];
    int kt = k>>5, kr = k&31;
    size_t idx = (((size_t)kt*4 + (n>>4))*64 + ((n&15) + ((kr>>3)<<4)))*8 + (kr&7);
    G[idx] = (f16)v;
    if (i < NN*HH){ hs[i]=0.f; cs[i]=0.f; }
}

// One time step. 1024 threads = 16 waves (16/CU resident, 50% occupancy).
// Block owns 16 node-rows. Wave w accumulates k-sixteenth [w*256, w*256+256).
// Two-stage LDS partial reduce; phase 2 on 512 threads, 1 dim each, no barriers.
__global__ __launch_bounds__(1024)
void step_kernel(const f16* __restrict__ Af, const f16* __restrict__ Gin,
                 f16* __restrict__ Gout,
                 const float* __restrict__ x, const float* __restrict__ W_out,
                 const float* __restrict__ b_out,
                 const float* __restrict__ Wgh, const float* __restrict__ bgh,
                 const float* __restrict__ Wgc, const float* __restrict__ bgc,
                 const float* __restrict__ Whc, const float* __restrict__ Whp,
                 const float* __restrict__ bh,
                 const float* __restrict__ Wcc, const float* __restrict__ Wcp,
                 const float* __restrict__ bc,
                 const float* __restrict__ K, const float* __restrict__ R,
                 const float* __restrict__ bias,
                 float* __restrict__ h_state, float* __restrict__ c_state,
                 float* __restrict__ out, int t)
{
    __shared__ float smem[12128];        // 48.5 KB
    float* ldsRed = smem;                // [8][16][64] partials (2-stage)
    float* gts    = smem;                // alias: [16][129] gates (phase 2)
    float* hgcg   = smem + 8192;         // [16][65]
    float* hprevL = smem + 9232;         // [16][33]
    float* xs     = smem + 9760;         // [16][16]
    float* hcur   = smem + 10016;        // [16][33]
    float* ccur   = smem + 10544;
    float* hupd   = smem + 11072;
    float* cupd   = smem + 11600;

    const int tid  = threadIdx.x;
    const int w    = tid >> 6;           // wave 0..15 = k-sixteenth
    const int lane = tid & 63;
    const int rb   = blockIdx.x;

    // ---------------- phase 1: fp16 MFMA, wave w = 8 kt ----------------
    f32x4 acc[4] = {};
    const f16x8* Ahp = (const f16x8*)Af;
    const f16x8* Gf  = (const f16x8*)Gin;
    size_t aIdx = ((size_t)rb*128 + w*8)*64 + lane;
    size_t gIdx = ((size_t)w*8)*256 + lane;
    #pragma unroll
    for (int kt = 0; kt < 8; ++kt, aIdx += 64, gIdx += 256){
        f16x8 ah = Ahp[aIdx];
        f16x8 g0 = Gf[gIdx], g1 = Gf[gIdx+64], g2 = Gf[gIdx+128], g3 = Gf[gIdx+192];
        acc[0] = __builtin_amdgcn_mfma_f32_16x16x32_f16(ah,g0,acc[0],0,0,0);
        acc[1] = __builtin_amdgcn_mfma_f32_16x16x32_f16(ah,g1,acc[1],0,0,0);
        acc[2] = __builtin_amdgcn_mfma_f32_16x16x32_f16(ah,g2,acc[2],0,0,0);
        acc[3] = __builtin_amdgcn_mfma_f32_16x16x32_f16(ah,g3,acc[3],0,0,0);
    }
    // C/D layout (m89): col = lane&15, row = (lane>>4)*4 + reg
    if (w < 8){
        #pragma unroll
        for (int ct = 0; ct < 4; ++ct)
            #pragma unroll
            for (int r = 0; r < 4; ++r){
                int mrow = ((lane>>4)<<2) + r;
                int mcol = ct*16 + (lane&15);
                ldsRed[(w<<10) + mrow*64 + mcol] = acc[ct][r];
            }
    }
    __syncthreads();
    if (w >= 8){
        #pragma unroll
        for (int ct = 0; ct < 4; ++ct)
            #pragma unroll
            for (int r = 0; r < 4; ++r){
                int mrow = ((lane>>4)<<2) + r;
                int mcol = ct*16 + (lane&15);
                ldsRed[((w-8)<<10) + mrow*64 + mcol] += acc[ct][r];
            }
    }
    __syncthreads();
    {   // final reduce: thread tid owns output element tid (16x64 = 1024)
        float s = 0.f;
        #pragma unroll
        for (int ww = 0; ww < 8; ++ww) s += ldsRed[(ww<<10) + tid];
        hgcg[(tid>>6)*65 + (tid&63)] = thf(s);
    }
    __syncthreads();

    // ---------------- phase 2: 512 threads, 1 dim each, no barriers ----------------
    if (tid < 512){
        const int r2 = tid >> 5;         // local row 0..15
        const int j  = tid & 31;         // h-dim 0..31
        const int row = rb*16 + r2;

        float hp = h_state[(size_t)row*HH + j];
        hprevL[r2*33 + j] = hp;
        if (j < 16) xs[r2*16 + j] = x[((size_t)row*TT + t)*FF + j];
        // wave-local group (32 consecutive lanes) -> in-order, no sync needed

        // gates: thread computes gate cols [j*4, j*4+4)
        float g4[4];
        #pragma unroll
        for (int q = 0; q < 4; ++q) g4[q] = bias[j*4 + q];
        #pragma unroll
        for (int f = 0; f < FF; ++f){
            float xv = xs[r2*16 + f];
            float4 k4 = *(const float4*)(K + f*128 + j*4);
            g4[0] += xv*k4.x; g4[1] += xv*k4.y; g4[2] += xv*k4.z; g4[3] += xv*k4.w;
        }
        #pragma unroll
        for (int i = 0; i < HH; ++i){
            float hv = hprevL[r2*33 + i];
            float4 r4 = *(const float4*)(R + i*128 + j*4);
            g4[0] += hv*r4.x; g4[1] += hv*r4.y; g4[2] += hv*r4.z; g4[3] += hv*r4.w;
        }
        #pragma unroll
        for (int q = 0; q < 4; ++q) gts[r2*129 + j*4 + q] = g4[q];

        // LSTM cell, dim j (gate order i,f,g,o)
        float gi = gts[r2*129 + j],      gf = gts[r2*129 + 32 + j];
        float gg = gts[r2*129 + 64 + j], go = gts[r2*129 + 96 + j];
        float cp = c_state[(size_t)row*HH + j];
        float cc = sigf(gf)*cp + sigf(gi)*thf(gg);
        float hc = sigf(go)*thf(cc);
        hcur[r2*33 + j] = hc;
        ccur[r2*33 + j] = cc;

        // fusion
        float s = bh[j], u = bc[j];
        #pragma unroll
        for (int i = 0; i < HH; ++i){
            float hcv = hcur[r2*33 + i], hgv = hgcg[r2*65 + i];
            float ccv = ccur[r2*33 + i], cgv = hgcg[r2*65 + 32 + i];
            s += hcv*Whc[i*32 + j] + hgv*Whp[i*32 + j];
            u += ccv*Wcc[i*32 + j] + cgv*Wcp[i*32 + j];
        }
        float hu = sigf(s), cu = sigf(u);
        hupd[r2*33 + j] = hu;
        cupd[r2*33 + j] = cu;
        h_state[(size_t)row*HH + j] = hu;
        c_state[(size_t)row*HH + j] = cu;

        // G(t+1), written straight into B-fragment order
        float gh = bgh[j], gc = bgc[j];
        #pragma unroll
        for (int i = 0; i < HH; ++i){
            float hv = hupd[r2*33 + i], cv = cupd[r2*33 + i];
            gh += hv*Wgh[i*32 + j];
            gc += cv*Wgc[i*32 + j];
        }
        {
            const int kt = row>>5, kr = row&31;
            const size_t tb = ((size_t)kt*4)*64;
            size_t i0 = (tb + (size_t)(j>>4)*64 + ((j&15) + ((kr>>3)<<4)))*8 + (kr&7);
            size_t i1 = (tb + (size_t)((HH+j)>>4)*64 + ((j&15) + ((kr>>3)<<4)))*8 + (kr&7);
            Gout[i0] = (f16)gh;
            Gout[i1] = (f16)gc;
        }

        // fused output head
        float p = hu * W_out[j];
        #pragma unroll
        for (int off = 16; off; off >>= 1) p += __shfl_down(p, off, 32);
        if (j == 0) out[(size_t)t*NN + row] = p + b_out[0];
    }
}

extern "C" void kernel_launch(void* const* d_in, const int* in_sizes, int n_in,
                              void* d_out, int out_size, void* d_ws, size_t ws_size,
                              hipStream_t stream)
{
    const float* x     = (const float*)d_in[0];
    const float* A     = (const float*)d_in[1];
    const float* W_out = (const float*)d_in[2];
    const float* b_out = (const float*)d_in[3];
    const float* Wgh   = (const float*)d_in[4];
    const float* bgh   = (const float*)d_in[5];
    const float* Wgc   = (const float*)d_in[6];
    const float* bgc   = (const float*)d_in[7];
    const float* Whc   = (const float*)d_in[8];
    const float* Whp   = (const float*)d_in[9];
    const float* bh    = (const float*)d_in[10];
    const float* Wcc   = (const float*)d_in[11];
    const float* Wcp   = (const float*)d_in[12];
    const float* bc    = (const float*)d_in[13];
    const float* K     = (const float*)d_in[14];
    const float* R     = (const float*)d_in[15];
    const float* bias  = (const float*)d_in[16];
    float* out = (float*)d_out;

    // ws: Af 32MB | G double-buffer 2x512KB | h/c state 1MB
    f16* Af = (f16*)d_ws;
    f16* G0 = Af + (size_t)NN*NN;
    f16* G1 = G0 + (size_t)NN*64;
    float* hs = (float*)(G1 + (size_t)NN*64);
    float* cs = hs + (size_t)NN*HH;

    prep_A<<<dim3(8192), dim3(256), 0, stream>>>(A, Af);
    init_G<<<dim3(1024), dim3(256), 0, stream>>>(G0, hs, cs, bgh, bgc);

    for (int t = 0; t < TT; ++t){
        const f16* Gin = (t & 1) ? G1 : G0;
        f16*       Gout = (t & 1) ? G0 : G1;
        step_kernel<<<dim3(NN/16), dim3(1024), 0, stream>>>(
            Af, Gin, Gout,
            x, W_out, b_out, Wgh, bgh, Wgc, bgc, Whc, Whp, bh,
            Wcc, Wcp, bc, K, R, bias, hs, cs, out, t);
    }
}